// Round 4
// baseline (445.962 us; speedup 1.0000x reference)
//
#include <hip/hip_runtime.h>
#include <hip/hip_fp16.h>

#define GG 256   // NUM_GRAPHS
#define ZZDIM 32 // Z
#define KK 64    // K
#define EMBD 10  // EMB
#define TILE (GG * ZZDIM)  // 8192 floats = 32 KB

// ---------------- kernels ----------------

// deg[i] = 2.0 (improved self-loop fill)
__global__ void init_kernel(float* __restrict__ deg, int n) {
    int i = blockIdx.x * blockDim.x + threadIdx.x;
    if (i < n) deg[i] = 2.0f;
}

// deg[col[e]] += w[e]
__global__ void deg_kernel(const int* __restrict__ col, const float* __restrict__ w,
                           float* __restrict__ deg, int e) {
    int i = blockIdx.x * blockDim.x + threadIdx.x;
    if (i < e) atomicAdd(&deg[col[i]], w[i]);
}

// hs[i,z] = rsqrt(deg[i]) * sum_j embed[x[i],j] * Wc[j,z];  dinv[i] = rsqrt(deg[i])
__global__ void hs_kernel(const int* __restrict__ x, const float* __restrict__ emb,
                          const float* __restrict__ Wc, const float* __restrict__ deg,
                          float* __restrict__ dinv, float* __restrict__ hs, int n) {
    int tid = blockIdx.x * blockDim.x + threadIdx.x;
    int i = tid >> 5, z = tid & 31;
    if (i >= n) return;
    float d = rsqrtf(deg[i]);            // deg >= 2 always (weights >= 0, self-loop 2.0)
    if (z == 0) dinv[i] = d;
    int xi = x[i];
    const float* er = emb + (long)xi * EMBD;
    float acc = 0.f;
#pragma unroll
    for (int j = 0; j < EMBD; ++j) acc += er[j] * Wc[j * ZZDIM + z];
    hs[(long)i * ZZDIM + z] = d * acc;
}

// pk[e] = (batch[col] << 16) | fp16(w * dinv[col])  — streaming + small L2 gathers
__global__ void prep_kernel(const int* __restrict__ col, const float* __restrict__ w,
                            const int* __restrict__ batch, const float* __restrict__ dinv,
                            unsigned int* __restrict__ pk, int e) {
    int i = blockIdx.x * blockDim.x + threadIdx.x;
    if (i >= e) return;
    int c = col[i];
    float cf = w[i] * dinv[c];
    unsigned int g = (unsigned int)batch[c];
    pk[i] = (g << 16) | (unsigned int)__half_as_ushort(__float2half_rn(cf));
}

// 32 lanes per item, 8 items per group-iteration (8 hs gathers in flight).
// LDS [256][32] unpadded (2-way cross-group aliasing = free). Flush = PLAIN coalesced
// stores into this block's private partial tile — zero global atomics here.
__global__ void __launch_bounds__(256) scatter_kernel(
    const int* __restrict__ row, const unsigned int* __restrict__ pk,
    const int* __restrict__ batch, const float* __restrict__ dinv,
    const float* __restrict__ hs, float* __restrict__ partial, int e, int n) {
    __shared__ float s[TILE];
    for (int i = threadIdx.x; i < TILE; i += 256) s[i] = 0.f;
    __syncthreads();

    const int z = threadIdx.x & 31;
    const long grp = blockIdx.x * 8L + (threadIdx.x >> 5);  // 8 groups/block

    // edges: 8 items per iteration (e % 8 == 0)
    const long estride = gridDim.x * 8L * 8L;
    for (long it = grp * 8; it + 7 < e; it += estride) {
        int4 ra = *(const int4*)(row + it);
        int4 rb = *(const int4*)(row + it + 4);
        uint4 pa = *(const uint4*)(pk + it);
        uint4 pb = *(const uint4*)(pk + it + 4);
        float v0 = hs[(long)ra.x * ZZDIM + z];
        float v1 = hs[(long)ra.y * ZZDIM + z];
        float v2 = hs[(long)ra.z * ZZDIM + z];
        float v3 = hs[(long)ra.w * ZZDIM + z];
        float v4 = hs[(long)rb.x * ZZDIM + z];
        float v5 = hs[(long)rb.y * ZZDIM + z];
        float v6 = hs[(long)rb.z * ZZDIM + z];
        float v7 = hs[(long)rb.w * ZZDIM + z];
        atomicAdd(&s[(pa.x >> 16) * ZZDIM + z],
                  __half2float(__ushort_as_half((unsigned short)(pa.x & 0xffffu))) * v0);
        atomicAdd(&s[(pa.y >> 16) * ZZDIM + z],
                  __half2float(__ushort_as_half((unsigned short)(pa.y & 0xffffu))) * v1);
        atomicAdd(&s[(pa.z >> 16) * ZZDIM + z],
                  __half2float(__ushort_as_half((unsigned short)(pa.z & 0xffffu))) * v2);
        atomicAdd(&s[(pa.w >> 16) * ZZDIM + z],
                  __half2float(__ushort_as_half((unsigned short)(pa.w & 0xffffu))) * v3);
        atomicAdd(&s[(pb.x >> 16) * ZZDIM + z],
                  __half2float(__ushort_as_half((unsigned short)(pb.x & 0xffffu))) * v4);
        atomicAdd(&s[(pb.y >> 16) * ZZDIM + z],
                  __half2float(__ushort_as_half((unsigned short)(pb.y & 0xffffu))) * v5);
        atomicAdd(&s[(pb.z >> 16) * ZZDIM + z],
                  __half2float(__ushort_as_half((unsigned short)(pb.z & 0xffffu))) * v6);
        atomicAdd(&s[(pb.w >> 16) * ZZDIM + z],
                  __half2float(__ushort_as_half((unsigned short)(pb.w & 0xffffu))) * v7);
    }

    // self-loops: 2*dinv[i]*hs[i] into batch[i]  (n % 4 == 0; coalesced reads)
    const long sstride = gridDim.x * 8L * 4L;
    for (long i = grp * 4; i + 3 < n; i += sstride) {
        int4 b4 = *(const int4*)(batch + i);
        float4 dv = *(const float4*)(dinv + i);
        float v0 = hs[(i + 0) * ZZDIM + z];
        float v1 = hs[(i + 1) * ZZDIM + z];
        float v2 = hs[(i + 2) * ZZDIM + z];
        float v3 = hs[(i + 3) * ZZDIM + z];
        atomicAdd(&s[b4.x * ZZDIM + z], 2.0f * dv.x * v0);
        atomicAdd(&s[b4.y * ZZDIM + z], 2.0f * dv.y * v1);
        atomicAdd(&s[b4.z * ZZDIM + z], 2.0f * dv.z * v2);
        atomicAdd(&s[b4.w * ZZDIM + z], 2.0f * dv.w * v3);
    }

    __syncthreads();
    float* r0 = partial + (long)blockIdx.x * TILE;
    for (int idx = threadIdx.x; idx < TILE; idx += 256)
        r0[idx] = s[idx];   // plain coalesced store, no atomics
}

// counts via binary search on sorted batch (no atomics)
__global__ void cnt_kernel(const int* __restrict__ batch, float* __restrict__ cnt, int n) {
    __shared__ int lb[GG + 1];
    int g = threadIdx.x;  // 256 threads
    int lo = 0, hi = n;
    while (lo < hi) {  // first index with batch[i] >= g
        int mid = (lo + hi) >> 1;
        if (batch[mid] < g) lo = mid + 1; else hi = mid;
    }
    lb[g] = lo;
    if (g == 0) lb[GG] = n;
    __syncthreads();
    cnt[g] = (float)(lb[g + 1] - lb[g]);
}

// reduce partials (8 wave-groups, stride-8 coalesced) -> pooled -> logits
__global__ void __launch_bounds__(256) finalize_kernel(
    const float* __restrict__ partial, int nblocks, const float* __restrict__ cnt,
    const float* __restrict__ bc, const float* __restrict__ Wr, float* __restrict__ out) {
    int g = blockIdx.x;
    int t = threadIdx.x;       // 256 threads
    int j = t >> 5, z = t & 31;
    __shared__ float sacc[8][ZZDIM];
    __shared__ float p[ZZDIM];

    const float* q = partial + g * ZZDIM + z;
    float acc = 0.f;
    for (int r = j; r < nblocks; r += 8)
        acc += q[(long)r * TILE];
    sacc[j][z] = acc;
    __syncthreads();

    if (t < ZZDIM) {
        float a = 0.f;
#pragma unroll
        for (int jj = 0; jj < 8; ++jj) a += sacc[jj][t];
        float c = cnt[g];
        float v = (c > 0.f) ? (bc[t] + a / c) : 0.f;
        out[g * ZZDIM + t] = v;
        p[t] = v;
    }
    __syncthreads();
    if (t < KK) {
        float a = 0.f;
#pragma unroll
        for (int zz = 0; zz < ZZDIM; ++zz) a += p[zz] * Wr[zz * KK + t];
        out[GG * ZZDIM + g * KK + t] = a;
    }
}

// ---------------- launch ----------------

extern "C" void kernel_launch(void* const* d_in, const int* in_sizes, int n_in,
                              void* d_out, int out_size, void* d_ws, size_t ws_size,
                              hipStream_t stream) {
    const int*   x     = (const int*)d_in[0];
    const int*   ei    = (const int*)d_in[1];   // [2,E]: rows then cols
    const float* ew    = (const float*)d_in[2];
    const int*   batch = (const int*)d_in[3];
    const float* emb   = (const float*)d_in[4];
    const float* Wc    = (const float*)d_in[5];
    const float* bc    = (const float*)d_in[6];
    const float* Wr    = (const float*)d_in[7];
    float* out = (float*)d_out;

    const int n = in_sizes[0];
    const int e = in_sizes[2];

    float* ws   = (float*)d_ws;
    float* deg  = ws;                        // n
    float* dinv = ws + n;                    // n
    float* hs   = ws + 2L * n;               // n*32
    float* cnt  = ws + 34L * n;              // 256
    unsigned int* pk = (unsigned int*)(cnt + GG);  // e
    long base = 34L * n + GG + e;
    base = (base + 63) & ~63L;               // align partials to 256 B
    float* partial = ws + base;

    // size the scatter grid by available workspace (each block owns one 32 KB tile)
    long avail = (long)(ws_size / 4) - base;
    int nblocks = (int)(avail / TILE);
    if (nblocks > 1280) nblocks = 1280;      // 5 blocks/CU ceiling
    if (nblocks < 64) nblocks = 64;          // ws is expected to cover this

    init_kernel<<<(n + 255) / 256, 256, 0, stream>>>(deg, n);
    deg_kernel<<<(e + 255) / 256, 256, 0, stream>>>(ei + e, ew, deg, e);
    hs_kernel<<<(n * 32 + 255) / 256, 256, 0, stream>>>(x, emb, Wc, deg, dinv, hs, n);
    prep_kernel<<<(e + 255) / 256, 256, 0, stream>>>(ei + e, ew, batch, dinv, pk, e);
    cnt_kernel<<<1, 256, 0, stream>>>(batch, cnt, n);
    scatter_kernel<<<nblocks, 256, 0, stream>>>(ei, pk, batch, dinv, hs, partial, e, n);
    finalize_kernel<<<GG, 256, 0, stream>>>(partial, nblocks, cnt, bc, Wr, out);
}

// Round 5
// 429.228 us; speedup vs baseline: 1.0390x; 1.0390x over previous
//
#include <hip/hip_runtime.h>

#define GG 256   // NUM_GRAPHS
#define ZZDIM 32 // Z
#define KK 64    // K
#define EMBD 10  // EMB
#define TILE (GG * ZZDIM)  // 8192 floats = 32 KB
#define NBLK 1024          // scatter grid: 4 blocks/CU * 256 CU

// ---------------- kernels ----------------

// deg[i] = 2.0 (improved self-loop fill)
__global__ void init_kernel(float* __restrict__ deg, int n) {
    int i = blockIdx.x * blockDim.x + threadIdx.x;
    if (i < n) deg[i] = 2.0f;
}

// deg[col[e]] += w[e], 4 edges/thread (low contention: 16 adds/line avg)
__global__ void deg_kernel(const int* __restrict__ col, const float* __restrict__ w,
                           float* __restrict__ deg, int e) {
    int i = (blockIdx.x * blockDim.x + threadIdx.x) * 4;
    if (i + 3 < e) {
        int4 c4 = *(const int4*)(col + i);
        float4 w4 = *(const float4*)(w + i);
        atomicAdd(&deg[c4.x], w4.x);
        atomicAdd(&deg[c4.y], w4.y);
        atomicAdd(&deg[c4.z], w4.z);
        atomicAdd(&deg[c4.w], w4.w);
    } else {
        for (; i < e; ++i) atomicAdd(&deg[col[i]], w[i]);
    }
}

// hs[i,z] = rsqrt(deg[i]) * sum_j embed[x[i],j] * Wc[j,z]
// nd[i] = (dinv_i, bitcast(batch_i))  — packed hot node data for scatter
__global__ void hs_kernel(const int* __restrict__ x, const float* __restrict__ emb,
                          const float* __restrict__ Wc, const float* __restrict__ deg,
                          const int* __restrict__ batch, float2* __restrict__ nd,
                          float* __restrict__ hs, int n) {
    int tid = blockIdx.x * blockDim.x + threadIdx.x;
    int i = tid >> 5, z = tid & 31;
    if (i >= n) return;
    float d = rsqrtf(deg[i]);            // deg >= 2 always (weights >= 0, self-loop 2.0)
    if (z == 0) nd[i] = make_float2(d, __int_as_float(batch[i]));
    int xi = x[i];
    const float* er = emb + (long)xi * EMBD;
    float acc = 0.f;
#pragma unroll
    for (int j = 0; j < EMBD; ++j) acc += er[j] * Wc[j * ZZDIM + z];
    hs[(long)i * ZZDIM + z] = d * acc;
}

// counts via binary search on sorted batch (no atomics)
__global__ void cnt_kernel(const int* __restrict__ batch, float* __restrict__ cnt, int n) {
    __shared__ int lb[GG + 1];
    int g = threadIdx.x;  // 256 threads
    int lo = 0, hi = n;
    while (lo < hi) {  // first index with batch[i] >= g
        int mid = (lo + hi) >> 1;
        if (batch[mid] < g) lo = mid + 1; else hi = mid;
    }
    lb[g] = lo;
    if (g == 0) lb[GG] = n;
    __syncthreads();
    cnt[g] = (float)(lb[g + 1] - lb[g]);
}

// 512 threads (16 groups of 32 lanes), 32 KB LDS tile -> 4 blocks/CU = 32 waves/CU.
// Per group-iteration: 8 edges -> 8 independent hs gathers + 8 hot nd gathers in flight.
// Flush: plain coalesced stores to this block's private partial tile.
__global__ void __launch_bounds__(512) scatter_kernel(
    const int* __restrict__ row, const int* __restrict__ col, const float* __restrict__ w,
    const float2* __restrict__ nd, const float* __restrict__ hs,
    float* __restrict__ partial, int e, int n) {
    __shared__ float s[TILE];
    for (int i = threadIdx.x; i < TILE; i += 512) s[i] = 0.f;
    __syncthreads();

    const int z = threadIdx.x & 31;
    const long grp = blockIdx.x * 16L + (threadIdx.x >> 5);  // 16 groups/block

    // edges: 8 per group-iteration
    const long estride = gridDim.x * 16L * 8L;
    for (long it = grp * 8; it + 7 < e; it += estride) {
        int4 ra = *(const int4*)(row + it);
        int4 rb = *(const int4*)(row + it + 4);
        int4 ca = *(const int4*)(col + it);
        int4 cb = *(const int4*)(col + it + 4);
        float4 wa = *(const float4*)(w + it);
        float4 wb = *(const float4*)(w + it + 4);
        float2 n0 = nd[ca.x];
        float2 n1 = nd[ca.y];
        float2 n2 = nd[ca.z];
        float2 n3 = nd[ca.w];
        float2 n4 = nd[cb.x];
        float2 n5 = nd[cb.y];
        float2 n6 = nd[cb.z];
        float2 n7 = nd[cb.w];
        float v0 = hs[(long)ra.x * ZZDIM + z];
        float v1 = hs[(long)ra.y * ZZDIM + z];
        float v2 = hs[(long)ra.z * ZZDIM + z];
        float v3 = hs[(long)ra.w * ZZDIM + z];
        float v4 = hs[(long)rb.x * ZZDIM + z];
        float v5 = hs[(long)rb.y * ZZDIM + z];
        float v6 = hs[(long)rb.z * ZZDIM + z];
        float v7 = hs[(long)rb.w * ZZDIM + z];
        atomicAdd(&s[__float_as_int(n0.y) * ZZDIM + z], wa.x * n0.x * v0);
        atomicAdd(&s[__float_as_int(n1.y) * ZZDIM + z], wa.y * n1.x * v1);
        atomicAdd(&s[__float_as_int(n2.y) * ZZDIM + z], wa.z * n2.x * v2);
        atomicAdd(&s[__float_as_int(n3.y) * ZZDIM + z], wa.w * n3.x * v3);
        atomicAdd(&s[__float_as_int(n4.y) * ZZDIM + z], wb.x * n4.x * v4);
        atomicAdd(&s[__float_as_int(n5.y) * ZZDIM + z], wb.y * n5.x * v5);
        atomicAdd(&s[__float_as_int(n6.y) * ZZDIM + z], wb.z * n6.x * v6);
        atomicAdd(&s[__float_as_int(n7.y) * ZZDIM + z], wb.w * n7.x * v7);
    }

    // self-loops: 2*dinv[i]*hs[i] into batch[i]  (coalesced nd reads)
    const long sstride = gridDim.x * 16L * 4L;
    for (long i = grp * 4; i + 3 < n; i += sstride) {
        float4 na = *(const float4*)(&nd[i]);      // nd[i], nd[i+1]
        float4 nb = *(const float4*)(&nd[i + 2]);  // nd[i+2], nd[i+3]
        float v0 = hs[(i + 0) * ZZDIM + z];
        float v1 = hs[(i + 1) * ZZDIM + z];
        float v2 = hs[(i + 2) * ZZDIM + z];
        float v3 = hs[(i + 3) * ZZDIM + z];
        atomicAdd(&s[__float_as_int(na.y) * ZZDIM + z], 2.0f * na.x * v0);
        atomicAdd(&s[__float_as_int(na.w) * ZZDIM + z], 2.0f * na.z * v1);
        atomicAdd(&s[__float_as_int(nb.y) * ZZDIM + z], 2.0f * nb.x * v2);
        atomicAdd(&s[__float_as_int(nb.w) * ZZDIM + z], 2.0f * nb.z * v3);
    }

    __syncthreads();
    float* r0 = partial + (long)blockIdx.x * TILE;
    for (int idx = threadIdx.x; idx < TILE; idx += 512)
        r0[idx] = s[idx];   // plain coalesced store, no atomics
}

// reduce partials (8 wave-groups, stride-8 coalesced) -> pooled -> logits
__global__ void __launch_bounds__(256) finalize_kernel(
    const float* __restrict__ partial, int nblocks, const float* __restrict__ cnt,
    const float* __restrict__ bc, const float* __restrict__ Wr, float* __restrict__ out) {
    int g = blockIdx.x;
    int t = threadIdx.x;       // 256 threads
    int j = t >> 5, z = t & 31;
    __shared__ float sacc[8][ZZDIM];
    __shared__ float p[ZZDIM];

    const float* q = partial + g * ZZDIM + z;
    float acc = 0.f;
    for (int r = j; r < nblocks; r += 8)
        acc += q[(long)r * TILE];
    sacc[j][z] = acc;
    __syncthreads();

    if (t < ZZDIM) {
        float a = 0.f;
#pragma unroll
        for (int jj = 0; jj < 8; ++jj) a += sacc[jj][t];
        float c = cnt[g];
        float v = (c > 0.f) ? (bc[t] + a / c) : 0.f;
        out[g * ZZDIM + t] = v;
        p[t] = v;
    }
    __syncthreads();
    if (t < KK) {
        float a = 0.f;
#pragma unroll
        for (int zz = 0; zz < ZZDIM; ++zz) a += p[zz] * Wr[zz * KK + t];
        out[GG * ZZDIM + g * KK + t] = a;
    }
}

// ---------------- launch ----------------

extern "C" void kernel_launch(void* const* d_in, const int* in_sizes, int n_in,
                              void* d_out, int out_size, void* d_ws, size_t ws_size,
                              hipStream_t stream) {
    const int*   x     = (const int*)d_in[0];
    const int*   ei    = (const int*)d_in[1];   // [2,E]: rows then cols
    const float* ew    = (const float*)d_in[2];
    const int*   batch = (const int*)d_in[3];
    const float* emb   = (const float*)d_in[4];
    const float* Wc    = (const float*)d_in[5];
    const float* bc    = (const float*)d_in[6];
    const float* Wr    = (const float*)d_in[7];
    float* out = (float*)d_out;

    const int n = in_sizes[0];
    const int e = in_sizes[2];

    float* ws   = (float*)d_ws;
    float* deg  = ws;                        // n
    float* hs   = ws + n;                    // n*32
    float2* nd  = (float2*)(ws + 33L * n);   // n float2 (33n is even -> 8B aligned)
    float* cnt  = ws + 35L * n;              // 256
    long base = 35L * n + GG;
    base = (base + 63) & ~63L;               // align partials to 256 B
    float* partial = ws + base;

    long avail = (long)(ws_size / 4) - base;
    int nblocks = (int)(avail / TILE);
    if (nblocks > NBLK) nblocks = NBLK;
    if (nblocks < 64) nblocks = 64;          // ws is expected to cover this

    init_kernel<<<(n + 255) / 256, 256, 0, stream>>>(deg, n);
    deg_kernel<<<(e / 4 + 255) / 256, 256, 0, stream>>>(ei + e, ew, deg, e);
    hs_kernel<<<(n * 32 + 255) / 256, 256, 0, stream>>>(x, emb, Wc, deg, batch, nd, hs, n);
    cnt_kernel<<<1, 256, 0, stream>>>(batch, cnt, n);
    scatter_kernel<<<nblocks, 512, 0, stream>>>(ei, ei + e, ew, nd, hs, partial, e, n);
    finalize_kernel<<<GG, 256, 0, stream>>>(partial, nblocks, cnt, bc, Wr, out);
}